// Round 1
// baseline (90.435 us; speedup 1.0000x reference)
//
#include <hip/hip_runtime.h>

// myAttention: B=1M batches, D=16, T=4.
// Per batch: x=[16,4] (cols = the 4 inputs), M = x^T x (4x4),
// att = softmax over rows (axis=1, per-column normalization),
// output[d] = sum_i x[d][i] * w[i],  w[i] = sum_j att[i][j].
// Memory-bound: 402 MB traffic -> ~64 us floor @ 6.3 TB/s.

__global__ __launch_bounds__(256) void myattn_kernel(
    const float* __restrict__ in0, const float* __restrict__ in1,
    const float* __restrict__ in2, const float* __restrict__ in3,
    float* __restrict__ out, float* __restrict__ att_out, int B)
{
    int b = blockIdx.x * blockDim.x + threadIdx.x;
    if (b >= B) return;
    size_t base = (size_t)b * 16;

    // Load x[q][d]: q = token slot (input index), d = feature. 4 x float4 each.
    float x[4][16];
    {
        const float* srcs[4] = {in0, in1, in2, in3};
        #pragma unroll
        for (int q = 0; q < 4; ++q) {
            const float4* p = reinterpret_cast<const float4*>(srcs[q] + base);
            #pragma unroll
            for (int v = 0; v < 4; ++v) {
                float4 t = p[v];
                x[q][v * 4 + 0] = t.x;
                x[q][v * 4 + 1] = t.y;
                x[q][v * 4 + 2] = t.z;
                x[q][v * 4 + 3] = t.w;
            }
        }
    }

    // M[i][j] = sum_d x[i][d] * x[j][d]  (symmetric, 10 unique dots)
    float M[4][4];
    #pragma unroll
    for (int i = 0; i < 4; ++i) {
        #pragma unroll
        for (int j = i; j < 4; ++j) {
            float s = 0.f;
            #pragma unroll
            for (int d = 0; d < 16; ++d) s = fmaf(x[i][d], x[j][d], s);
            M[i][j] = s;
            M[j][i] = s;
        }
    }

    // softmax over axis=1 (rows i), separately for each column j
    float att[4][4];
    #pragma unroll
    for (int j = 0; j < 4; ++j) {
        float m = fmaxf(fmaxf(M[0][j], M[1][j]), fmaxf(M[2][j], M[3][j]));
        float e0 = __expf(M[0][j] - m);
        float e1 = __expf(M[1][j] - m);
        float e2 = __expf(M[2][j] - m);
        float e3 = __expf(M[3][j] - m);
        float inv = 1.f / (e0 + e1 + e2 + e3);
        att[0][j] = e0 * inv;
        att[1][j] = e1 * inv;
        att[2][j] = e2 * inv;
        att[3][j] = e3 * inv;
    }

    // w[i] = sum_j att[i][j];  output[d] = sum_i x[i][d] * w[i]
    float w[4];
    #pragma unroll
    for (int i = 0; i < 4; ++i)
        w[i] = att[i][0] + att[i][1] + att[i][2] + att[i][3];

    float4* po = reinterpret_cast<float4*>(out + base);
    #pragma unroll
    for (int v = 0; v < 4; ++v) {
        float4 t;
        t.x = fmaf(x[0][v*4+0], w[0], fmaf(x[1][v*4+0], w[1], fmaf(x[2][v*4+0], w[2], x[3][v*4+0] * w[3])));
        t.y = fmaf(x[0][v*4+1], w[0], fmaf(x[1][v*4+1], w[1], fmaf(x[2][v*4+1], w[2], x[3][v*4+1] * w[3])));
        t.z = fmaf(x[0][v*4+2], w[0], fmaf(x[1][v*4+2], w[1], fmaf(x[2][v*4+2], w[2], x[3][v*4+2] * w[3])));
        t.w = fmaf(x[0][v*4+3], w[0], fmaf(x[1][v*4+3], w[1], fmaf(x[2][v*4+3], w[2], x[3][v*4+3] * w[3])));
        po[v] = t;
    }

    // att output: [B, i, j] row-major -> one float4 per row i
    float4* pa = reinterpret_cast<float4*>(att_out + base);
    #pragma unroll
    for (int i = 0; i < 4; ++i)
        pa[i] = make_float4(att[i][0], att[i][1], att[i][2], att[i][3]);
}

extern "C" void kernel_launch(void* const* d_in, const int* in_sizes, int n_in,
                              void* d_out, int out_size, void* d_ws, size_t ws_size,
                              hipStream_t stream) {
    int B = in_sizes[0] / 16;
    const float* in0 = (const float*)d_in[0];
    const float* in1 = (const float*)d_in[1];
    const float* in2 = (const float*)d_in[2];
    const float* in3 = (const float*)d_in[3];
    float* out = (float*)d_out;
    float* att = out + (size_t)B * 16;

    const int threads = 256;
    const int blocks = (B + threads - 1) / threads;
    myattn_kernel<<<blocks, threads, 0, stream>>>(in0, in1, in2, in3, out, att, B);
}